// Round 9
// baseline (194.494 us; speedup 1.0000x reference)
//
#include <hip/hip_runtime.h>
#include <math.h>

#define BB 16
#define MM 2048
#define SS 6
#define EE 128
#define LCC 512
#define VV 32000

typedef __attribute__((ext_vector_type(8))) __bf16 bf16x8;
typedef __attribute__((ext_vector_type(4))) float f32x4;

#define XS_STRIDE 264   // 256+8 bf16 pad
#define HS_STRIDE 136   // 128+8 bf16 pad

// ---------------------------------------------------------------------------
// megaprep: fp32->bf16 of C[0..3), dh, tf; weight transpose; uqA=uqB=0.
// One streaming dispatch (~72 MB, ~15 us). Absorbs prep_small.
// ---------------------------------------------------------------------------
static __device__ inline void cvt8(const float* __restrict__ src, __bf16* __restrict__ dst) {
    const float4 a = *(const float4*)src;
    const float4 b = *(const float4*)(src + 4);
    bf16x8 o;
    o[0] = (__bf16)a.x; o[1] = (__bf16)a.y; o[2] = (__bf16)a.z; o[3] = (__bf16)a.w;
    o[4] = (__bf16)b.x; o[5] = (__bf16)b.y; o[6] = (__bf16)b.z; o[7] = (__bf16)b.w;
    *(bf16x8*)dst = o;
}

#define N_C8  (3 * VV * EE / 8)        // 1,536,000
#define N_D8  (BB * LCC * EE / 8)      // 131,072
#define N_T8  (BB * EE / 8)            // 256
#define N_W1  (256 * 128)              // 32,768
#define N_W2  (128 * 128)              // 16,384
#define N_UQ  (BB * EE)                // 2,048
#define N_PREP (N_C8 + N_D8 + N_T8 + N_W1 + N_W2 + N_UQ)

__global__ __launch_bounds__(256)
void megaprep(const float* __restrict__ C, const float* __restrict__ dh,
              const float* __restrict__ tf, const float* __restrict__ W1,
              const float* __restrict__ W2,
              __bf16* __restrict__ Cb, __bf16* __restrict__ dhb,
              __bf16* __restrict__ tfb, __bf16* __restrict__ w1t,
              __bf16* __restrict__ w2t, float* __restrict__ uqA,
              float* __restrict__ uqB)
{
    int i = blockIdx.x * 256 + threadIdx.x;
    if (i < N_C8) { cvt8(C + (size_t)i * 8, Cb + (size_t)i * 8); return; }
    i -= N_C8;
    if (i < N_D8) { cvt8(dh + (size_t)i * 8, dhb + (size_t)i * 8); return; }
    i -= N_D8;
    if (i < N_T8) { cvt8(tf + i * 8, tfb + i * 8); return; }
    i -= N_T8;
    if (i < N_W1) { const int n = i >> 8, k = i & 255; w1t[i] = (__bf16)W1[k * EE + n]; return; }
    i -= N_W1;
    if (i < N_W2) { const int n = i >> 7, k = i & 127; w2t[i] = (__bf16)W2[k * EE + n]; return; }
    i -= N_W2;
    if (i < N_UQ) { uqA[i] = 0.f; uqB[i] = 0.f; }
}

// ---------------------------------------------------------------------------
// Fused embed gather-sum (bf16 table: half the L2-miss bytes) + add_lm +
// MFMA MLP, 3 hops in one grid. hop 0: logits0 in-register, m0 never stored.
// LDS: Hs/plog alias Xs -> 17.7 KB -> 8 blocks/CU.
// ---------------------------------------------------------------------------
__global__ __launch_bounds__(256)
void embed_mlp_mfma(const int* __restrict__ story,
                    const int* __restrict__ kb_len,
                    const int* __restrict__ conv_len,
                    const __bf16* __restrict__ Cb,
                    const __bf16* __restrict__ dhb,
                    const __bf16* __restrict__ tfb,
                    const __bf16* __restrict__ w1t, const float* __restrict__ b1,
                    const __bf16* __restrict__ w2t, const float* __restrict__ b2,
                    const float* __restrict__ gp, const float* __restrict__ query,
                    __bf16* __restrict__ mout, float* __restrict__ lbuf0)
{
    __shared__ __bf16 Xs[32 * XS_STRIDE];   // 16,896 B; Hs (8,704 B) aliases
    __shared__ int    sidx[32 * SS];
    __bf16* Hs   = Xs;                      // Xs dead before H written (barrier)
    float*  plog = (float*)Xs;              // Hs dead before plog written

    const int bid  = blockIdx.x;
    const int hop  = bid >> 10;
    const int row0 = (bid & 1023) * 32;
    const int b    = row0 >> 11;
    const int tid  = threadIdx.x;

    const __bf16* Ck = Cb + (size_t)hop * VV * EE;

    for (int i = tid; i < 32 * SS; i += 256) sidx[i] = story[(size_t)row0 * SS + i];

    const int kb   = kb_len[b];
    const int cl   = conv_len[b];
    const int rgrp = tid >> 4;              // 0..15
    const int e8   = (tid & 15) * 8;
    const bf16x8 tf8 = *(const bf16x8*)&tfb[b * EE + e8];
    __syncthreads();

    // ---- gather: 2 passes x 16 rows; all loads issued before use ----
    bf16x8 g[2][SS], dv[2];
    #pragma unroll
    for (int p = 0; p < 2; ++p) {
        const int r = p * 16 + rgrp;
        const int* si = &sidx[r * SS];
        #pragma unroll
        for (int s = 0; s < SS; ++s)
            g[p][s] = *(const bf16x8*)&Ck[(size_t)si[s] * EE + e8];
        const int j = ((row0 + r) & (MM - 1)) - kb;
        if (j >= 0 && j < cl) {
            dv[p] = *(const bf16x8*)&dhb[((size_t)b * LCC + j) * EE + e8];
        } else {
            bf16x8 z;
            #pragma unroll
            for (int q = 0; q < 8; ++q) z[q] = (__bf16)0.f;
            dv[p] = z;
        }
    }
    #pragma unroll
    for (int p = 0; p < 2; ++p) {
        const int r = p * 16 + rgrp;
        bf16x8 pk;
        #pragma unroll
        for (int q = 0; q < 8; ++q) {
            float s = (float)dv[p][q];
            #pragma unroll
            for (int s6 = 0; s6 < SS; ++s6) s += (float)g[p][s6][q];
            pk[q] = (__bf16)s;
        }
        *(bf16x8*)&Xs[r * XS_STRIDE + e8]      = pk;
        *(bf16x8*)&Xs[r * XS_STRIDE + EE + e8] = tf8;
    }
    __syncthreads();

    const int w       = tid >> 6;
    const int lane    = tid & 63;
    const int lr      = lane & 15;
    const int lk      = lane >> 4;
    const int colbase = w * 32;

    // ---- GEMM1: H = lrelu(X @ W1 + b1) ----
    f32x4 acc1[2][2];
    #pragma unroll
    for (int i = 0; i < 2; ++i)
        #pragma unroll
        for (int j = 0; j < 2; ++j) acc1[i][j] = (f32x4){0.f, 0.f, 0.f, 0.f};

    for (int ks = 0; ks < 8; ++ks) {
        bf16x8 a[2], bw[2];
        #pragma unroll
        for (int mt = 0; mt < 2; ++mt)
            a[mt] = *(const bf16x8*)&Xs[(mt * 16 + lr) * XS_STRIDE + ks * 32 + lk * 8];
        #pragma unroll
        for (int nt = 0; nt < 2; ++nt)
            bw[nt] = *(const bf16x8*)&w1t[(size_t)(colbase + nt * 16 + lr) * 256 + ks * 32 + lk * 8];
        #pragma unroll
        for (int mt = 0; mt < 2; ++mt)
            #pragma unroll
            for (int nt = 0; nt < 2; ++nt)
                acc1[mt][nt] = __builtin_amdgcn_mfma_f32_16x16x32_bf16(a[mt], bw[nt], acc1[mt][nt], 0, 0, 0);
    }
    __syncthreads();   // all Xs reads complete before Hs (alias) written
    {
        const float b1v[2] = { b1[colbase + lr], b1[colbase + 16 + lr] };
        #pragma unroll
        for (int mt = 0; mt < 2; ++mt)
            #pragma unroll
            for (int nt = 0; nt < 2; ++nt)
                #pragma unroll
                for (int reg = 0; reg < 4; ++reg) {
                    float h = acc1[mt][nt][reg] + b1v[nt];
                    h = (h > 0.f) ? h : 0.1f * h;
                    Hs[(mt * 16 + lk * 4 + reg) * HS_STRIDE + colbase + nt * 16 + lr] = (__bf16)h;
                }
    }
    __syncthreads();

    // ---- GEMM2: Y = H @ W2 + b2 ----
    f32x4 acc2[2][2];
    #pragma unroll
    for (int i = 0; i < 2; ++i)
        #pragma unroll
        for (int j = 0; j < 2; ++j) acc2[i][j] = (f32x4){0.f, 0.f, 0.f, 0.f};

    for (int ks = 0; ks < 4; ++ks) {
        bf16x8 a[2], bw[2];
        #pragma unroll
        for (int mt = 0; mt < 2; ++mt)
            a[mt] = *(const bf16x8*)&Hs[(mt * 16 + lr) * HS_STRIDE + ks * 32 + lk * 8];
        #pragma unroll
        for (int nt = 0; nt < 2; ++nt)
            bw[nt] = *(const bf16x8*)&w2t[(size_t)(colbase + nt * 16 + lr) * 128 + ks * 32 + lk * 8];
        #pragma unroll
        for (int mt = 0; mt < 2; ++mt)
            #pragma unroll
            for (int nt = 0; nt < 2; ++nt)
                acc2[mt][nt] = __builtin_amdgcn_mfma_f32_16x16x32_bf16(a[mt], bw[nt], acc2[mt][nt], 0, 0, 0);
    }

    const float b2v[2] = { b2[colbase + lr], b2[colbase + 16 + lr] };

    if (hop == 0) {
        const float qv0 = query[b * EE + colbase + lr];
        const float qv1 = query[b * EE + colbase + 16 + lr];
        __syncthreads();    // Hs reads done; reuse as plog
        #pragma unroll
        for (int mt = 0; mt < 2; ++mt)
            #pragma unroll
            for (int reg = 0; reg < 4; ++reg) {
                float p = (acc2[mt][0][reg] + b2v[0]) * qv0
                        + (acc2[mt][1][reg] + b2v[1]) * qv1;
                p += __shfl_xor(p, 1, 64);
                p += __shfl_xor(p, 2, 64);
                p += __shfl_xor(p, 4, 64);
                p += __shfl_xor(p, 8, 64);
                if (lr == 0) plog[(mt * 16 + lk * 4 + reg) * 4 + w] = p;
            }
        __syncthreads();
        if (tid < 32) {
            const float l = plog[tid * 4] + plog[tid * 4 + 1] + plog[tid * 4 + 2] + plog[tid * 4 + 3];
            lbuf0[row0 + tid] = l * gp[row0 + tid];
        }
    } else {
        __bf16* out = mout + (size_t)(hop - 1) * 32768 * EE;
        #pragma unroll
        for (int mt = 0; mt < 2; ++mt)
            #pragma unroll
            for (int nt = 0; nt < 2; ++nt)
                #pragma unroll
                for (int reg = 0; reg < 4; ++reg) {
                    const int rg_ = row0 + mt * 16 + lk * 4 + reg;
                    out[(size_t)rg_ * EE + colbase + nt * 16 + lr] =
                        (__bf16)(acc2[mt][nt][reg] + b2v[nt]);
                }
    }
}

// ---------------------------------------------------------------------------
// update: inline softmax of lbuf[b,:], then uq[b,:] += sum_{64 rows} gp*soft*mk.
// 512 blocks x 256.
// ---------------------------------------------------------------------------
__global__ __launch_bounds__(256)
void update_kernel(const __bf16* __restrict__ mk, const float* __restrict__ gp,
                   const float* __restrict__ lbuf, float* __restrict__ uq)
{
    __shared__ float redm[4], reds[4];
    __shared__ float wls[64];
    __shared__ float part[4][128];

    const int b      = blockIdx.x >> 5;
    const int rloc0  = (blockIdx.x & 31) * 64;
    const int tid    = threadIdx.x;
    const int lane   = tid & 63;
    const int w      = tid >> 6;
    const float* lb  = lbuf + (size_t)b * MM;

    float v[8];
    float mx = -1e30f;
    #pragma unroll
    for (int i = 0; i < 8; ++i) { v[i] = lb[i * 256 + tid]; mx = fmaxf(mx, v[i]); }
    #pragma unroll
    for (int off = 32; off > 0; off >>= 1) mx = fmaxf(mx, __shfl_xor(mx, off, 64));
    if (lane == 0) redm[w] = mx;
    __syncthreads();
    mx = fmaxf(fmaxf(redm[0], redm[1]), fmaxf(redm[2], redm[3]));
    float sum = 0.f;
    #pragma unroll
    for (int i = 0; i < 8; ++i) sum += __expf(v[i] - mx);
    #pragma unroll
    for (int off = 32; off > 0; off >>= 1) sum += __shfl_xor(sum, off, 64);
    if (lane == 0) reds[w] = sum;
    __syncthreads();
    const float inv = 1.f / (reds[0] + reds[1] + reds[2] + reds[3]);

    if (tid < 64)
        wls[tid] = gp[(size_t)b * MM + rloc0 + tid] * __expf(lb[rloc0 + tid] - mx) * inv;
    __syncthreads();

    const int rgrp = tid >> 4;
    const int e8   = (tid & 15) * 8;
    float acc[8];
    #pragma unroll
    for (int q = 0; q < 8; ++q) acc[q] = 0.f;
    #pragma unroll
    for (int p = 0; p < 4; ++p) {
        const int rl  = p * 16 + rgrp;
        const float wg = wls[rl];
        const bf16x8 vv = *(const bf16x8*)&mk[((size_t)b * MM + rloc0 + rl) * EE + e8];
        #pragma unroll
        for (int q = 0; q < 8; ++q) acc[q] += wg * (float)vv[q];
    }
    #pragma unroll
    for (int q = 0; q < 8; ++q) {
        acc[q] += __shfl_xor(acc[q], 16, 64);
        acc[q] += __shfl_xor(acc[q], 32, 64);
    }
    if (lane < 16) {
        #pragma unroll
        for (int q = 0; q < 8; ++q) part[w][e8 + q] = acc[q];
    }
    __syncthreads();
    if (tid < 128) {
        const float s = part[0][tid] + part[1][tid] + part[2][tid] + part[3][tid];
        atomicAdd(&uq[b * EE + tid], s);
    }
}

// ---------------------------------------------------------------------------
// logits[row] = gp[row] * dot(mk[row,:], query[b]+uqa[b](+uqb[b])).
// 512 blocks x 64 rows.
// ---------------------------------------------------------------------------
__global__ __launch_bounds__(256)
void logits_kernel(const __bf16* __restrict__ mk, const float* __restrict__ gp,
                   const float* __restrict__ query, const float* __restrict__ uqa,
                   const float* __restrict__ uqb, float* __restrict__ out)
{
    __shared__ float uqs[128];
    const int row0 = blockIdx.x * 64;
    const int b    = row0 >> 11;
    const int tid  = threadIdx.x;
    if (tid < 128)
        uqs[tid] = query[b * EE + tid] + uqa[b * EE + tid]
                 + (uqb ? uqb[b * EE + tid] : 0.f);
    __syncthreads();
    const int w = tid >> 6, lane = tid & 63;
    const int g = lane >> 4, l16 = lane & 15;
    float u[8];
    #pragma unroll
    for (int j = 0; j < 8; ++j) u[j] = uqs[l16 * 8 + j];
    #pragma unroll
    for (int it = 0; it < 4; ++it) {
        const int row = row0 + it * 16 + w * 4 + g;
        const bf16x8 v = *(const bf16x8*)&mk[(size_t)row * EE + l16 * 8];
        float p = 0.f;
        #pragma unroll
        for (int j = 0; j < 8; ++j) p += (float)v[j] * u[j];
        p += __shfl_xor(p, 1, 64);
        p += __shfl_xor(p, 2, 64);
        p += __shfl_xor(p, 4, 64);
        p += __shfl_xor(p, 8, 64);
        if (l16 == 0) out[row] = p * gp[row];
    }
}

// ---------------------------------------------------------------------------
// final softmax: block per b.
// ---------------------------------------------------------------------------
__global__ __launch_bounds__(256)
void softmax_final(const float* __restrict__ logits, float* __restrict__ soft)
{
    __shared__ float redm[4], reds[4];
    const int b = blockIdx.x, tid = threadIdx.x;
    const int lane = tid & 63, w = tid >> 6;
    const float* lb = logits + (size_t)b * MM;
    float v[8];
    float mx = -1e30f;
    #pragma unroll
    for (int i = 0; i < 8; ++i) { v[i] = lb[i * 256 + tid]; mx = fmaxf(mx, v[i]); }
    #pragma unroll
    for (int off = 32; off > 0; off >>= 1) mx = fmaxf(mx, __shfl_xor(mx, off, 64));
    if (lane == 0) redm[w] = mx;
    __syncthreads();
    mx = fmaxf(fmaxf(redm[0], redm[1]), fmaxf(redm[2], redm[3]));
    float sum = 0.f;
    #pragma unroll
    for (int i = 0; i < 8; ++i) { v[i] = __expf(v[i] - mx); sum += v[i]; }
    #pragma unroll
    for (int off = 32; off > 0; off >>= 1) sum += __shfl_xor(sum, off, 64);
    if (lane == 0) reds[w] = sum;
    __syncthreads();
    const float inv = 1.f / (reds[0] + reds[1] + reds[2] + reds[3]);
    #pragma unroll
    for (int i = 0; i < 8; ++i) soft[(size_t)b * MM + i * 256 + tid] = v[i] * inv;
}

// ---------------------------------------------------------------------------
extern "C" void kernel_launch(void* const* d_in, const int* in_sizes, int n_in,
                              void* d_out, int out_size, void* d_ws, size_t ws_size,
                              hipStream_t stream) {
    const int*   story    = (const int*)d_in[0];
    const int*   kb_len   = (const int*)d_in[1];
    const int*   conv_len = (const int*)d_in[2];
    // d_in[3] = hidden (dead w.r.t. outputs)
    const float* dh       = (const float*)d_in[4];
    const float* tf       = (const float*)d_in[5];
    const float* query    = (const float*)d_in[6];
    const float* gp       = (const float*)d_in[7];
    const float* C        = (const float*)d_in[8];
    const float* wA1      = (const float*)d_in[9];
    const float* bA1      = (const float*)d_in[10];
    const float* wA2      = (const float*)d_in[11];
    const float* bA2      = (const float*)d_in[12];
    // wC1/bC1/wC2/bC2, wf/bf: dead w.r.t. outputs

    char* ws = (char*)d_ws;
    const size_t M_ELEMS = (size_t)32768 * EE;
    size_t off = 0;
    __bf16* m   = (__bf16*)(ws + off); off += 2 * M_ELEMS * sizeof(__bf16);    // m1, m2
    __bf16* Cb  = (__bf16*)(ws + off); off += (size_t)3 * VV * EE * sizeof(__bf16);
    __bf16* dhb = (__bf16*)(ws + off); off += (size_t)BB * LCC * EE * sizeof(__bf16);
    __bf16* tfb = (__bf16*)(ws + off); off += (size_t)BB * EE * sizeof(__bf16);
    __bf16* w1t = (__bf16*)(ws + off); off += 256 * 128 * sizeof(__bf16);
    __bf16* w2t = (__bf16*)(ws + off); off += 128 * 128 * sizeof(__bf16);
    float* lbuf = (float*)(ws + off);  off += (size_t)BB * MM * sizeof(float);
    float* uqA  = (float*)(ws + off);  off += (size_t)BB * EE * sizeof(float);
    float* uqB  = (float*)(ws + off);  off += (size_t)BB * EE * sizeof(float);

    float* out_soft   = (float*)d_out;
    float* out_logits = out_soft + (size_t)BB * MM;

    megaprep<<<(N_PREP + 255) / 256, 256, 0, stream>>>(C, dh, tf, wA1, wA2,
                                                       Cb, dhb, tfb, w1t, w2t,
                                                       uqA, uqB);
    embed_mlp_mfma<<<3072, 256, 0, stream>>>(story, kb_len, conv_len, Cb, dhb, tfb,
                                             w1t, bA1, w2t, bA2, gp, query, m, lbuf);
    // hop1: uqA = m1^T(gp*soft0);  logits1 = gp*(m1 (query+uqA)) -> lbuf
    update_kernel<<<512, 256, 0, stream>>>(m, gp, lbuf, uqA);
    logits_kernel<<<512, 256, 0, stream>>>(m, gp, query, uqA, nullptr, lbuf);
    // hop2: uqB = m2^T(gp*soft1);  logits2 = gp*(m2 (query+uqA+uqB)) -> out
    update_kernel<<<512, 256, 0, stream>>>(m + M_ELEMS, gp, lbuf, uqB);
    logits_kernel<<<512, 256, 0, stream>>>(m + M_ELEMS, gp, query, uqA, uqB, out_logits);
    softmax_final<<<BB, 256, 0, stream>>>(out_logits, out_soft);
}